// Round 5
// baseline (197.697 us; speedup 1.0000x reference)
//
#include <hip/hip_runtime.h>

// Boundary_binaryLoss: 15x15 binary morphology boundary mask + masked NLL mean.
// B=32, C=2, H=480, W=864. logits [B,C,H,W] f32, labels [B,H,W] i32 in {0,1,255}.
//
// valid(b,h,w) = (label != 255) && (clipped 15x15 window has a px with
//   np_label==0 (label 0 or 255) AND a px with np_label==255 (label 1))
// loss = -sum(valid ? logits[b,label,h,w] : 0) / max(#valid, 1)
//
// R1: atomics -> partials. 66us.  R2: reg prefetch sunk (VGPR=24). 66us.
// R3: global_load_lds (drained by __syncthreads). 65us, occ 44%.
// R4: barrier-free waves, scalar loads. 65us, occ 46%.
// R5: fat loads, load-all arrays -> VGPR-64 spill, WRITE 130MB. 91us.
// R6: fat loads, fused fold, spill-free (WRITE 60KB, VGPR 80). STILL 63us,
//     occ 25%. CONCLUSION: occupancy 25..63%, request width 4..16B, barriers,
//     bank conflicts -- all no effect. The invariant across every version is
//     total cache-line traffic (~200-260 MB touched) at an effective
//     ~4 TB/s => duration ~ bytes/4TB/s. Only lever: touch fewer bytes.
// R7: TH 8 -> 32. Label halo 22/8=2.75x -> 46/32=1.44x: touched bytes
//     257 -> ~185 MB. Flags per column: 92 bits in (lo,hi) u64 pair;
//     vertical 15-OR via 128-bit emulated shift-OR doubling. Logits in 4
//     row-groups of 8, explicit named double buffers (static indexing only).
//     1-wave blocks (no barrier at all), bijective XCD swizzle (1920%8==0)
//     so each XCD streams 4 whole images; vertical neighbors share L2 lines.
//     Falsifiable: dur -> 46-50us if line-traffic theory holds; WRITE ~60KB.

namespace {
constexpr int B_ = 32;
constexpr int H_ = 480;
constexpr int W_ = 864;
constexpr int HW = H_ * W_;
constexpr int R_ = 7;
constexpr int TH_ = 32;                  // output rows per wave
constexpr int LH = TH_ + 2 * R_;         // 46 label rows read
constexpr int SW = 216;                  // output cols per strip
constexpr int NSX = W_ / SW;             // 4 (exact)
constexpr int NSY = H_ / TH_;            // 15
constexpr int NTILE = B_ * NSY * NSX;    // 1920 wave-tiles = blocks
} // namespace

typedef unsigned long long u64;

__device__ __forceinline__ u64 shfl_up64(u64 x, int d) {
  return __shfl_up(x, d, 64);
}
__device__ __forceinline__ u64 shfl_dn64(u64 x, int d) {
  return __shfl_down(x, d, 64);
}

// 128-bit (lo,hi) shift-OR doubling: lo bit 2o := OR_{d=0..14} bit 2(o+d).
__device__ __forceinline__ void vfold15(u64& lo, u64 hi) {
  u64 l = lo, h = hi;
  l |= (l >> 2) | (h << 62);   h |= h >> 2;
  l |= (l >> 4) | (h << 60);   h |= h >> 4;
  l |= (l >> 8) | (h << 56);   h |= h >> 8;
  l |= (l >> 14) | (h << 50);
  lo = l;
}

extern "C" __global__ __launch_bounds__(64, 2)
void boundary_loss_main(const float* __restrict__ logits,
                        const int* __restrict__ labels,
                        double2* __restrict__ partials)
{
  const int lane = threadIdx.x;               // 0..63 (one wave per block)
  const int bid = blockIdx.x;
  // bijective XCD swizzle (NTILE % 8 == 0): XCD k gets tiles [k*240,(k+1)*240)
  // = 4 complete images, sx fastest then sy -> vertical halo reuse in L2.
  const int lb = (bid & 7) * (NTILE / 8) + (bid >> 3);
  const int b = lb / (NSY * NSX);
  const int rr = lb - b * (NSY * NSX);
  const int sy = rr >> 2;                     // NSX == 4
  const int sx = rr & 3;

  const int gr0 = sy * TH_;                   // first output image row
  const int cb0 = sx * SW - 8 + 4 * lane;     // this lane's 4-col base
  const bool colinb = (cb0 >= 0) && (cb0 + 3 < W_);
  const int cbc = colinb ? cb0 : (cb0 < 0 ? 0 : W_ - 4);

  const int* __restrict__ lab = labels + b * HW + cbc;
  const float* __restrict__ lg = logits + (size_t)(2 * b) * HW;

  // ---- phase 1: FUSED label load+fold, 46x int4 (1KB/wave requests) ----
  // f (2 bits / label row, cols j=0..3): bit0 np==0 (label 0/255),
  //   bit1 np==255 (label 1). rows 0..31 in fL, rows 32..45 in fH.
  // cp (2 bits / OUTPUT row): bit0 label==1 (chan sel), bit1 ignore.
  u64 fL0 = 0, fL1 = 0, fL2 = 0, fL3 = 0;
  u64 fH0 = 0, fH1 = 0, fH2 = 0, fH3 = 0;
  u64 cp0 = 0, cp1 = 0, cp2 = 0, cp3 = 0;
#pragma unroll
  for (int a = 0; a < LH; ++a) {
    int gr = gr0 - R_ + a;
    gr = gr < 0 ? 0 : (gr >= H_ ? H_ - 1 : gr);   // clamped; masked below
    const int4 v = *(const int4*)(lab + gr * W_);
    const u64 e1x = (v.x == 1), e1y = (v.y == 1),
              e1z = (v.z == 1), e1w = (v.w == 1);
    if (a < 32) {
      const int sh = 2 * a;
      fL0 |= (1ull + e1x) << sh;  fL1 |= (1ull + e1y) << sh;
      fL2 |= (1ull + e1z) << sh;  fL3 |= (1ull + e1w) << sh;
    } else {
      const int sh = 2 * (a - 32);
      fH0 |= (1ull + e1x) << sh;  fH1 |= (1ull + e1y) << sh;
      fH2 |= (1ull + e1z) << sh;  fH3 |= (1ull + e1w) << sh;
    }
    if (a >= R_ && a < R_ + TH_) {
      const int sh = 2 * (a - R_);
      cp0 |= (e1x | ((u64)(v.x == 255) << 1)) << sh;
      cp1 |= (e1y | ((u64)(v.y == 255) << 1)) << sh;
      cp2 |= (e1z | ((u64)(v.z == 255) << 1)) << sh;
      cp3 |= (e1w | ((u64)(v.w == 255) << 1)) << sh;
    }
  }
  // clip: OOB image rows / OOB lane columns contribute nothing
  {
    u64 mLo = ~0ull, mHi = (1ull << 28) - 1;
    if (gr0 == 0) mLo &= (~0ull) << (2 * R_);          // a < 7 invalid
    if (gr0 == H_ - TH_) mHi &= (1ull << 14) - 1;      // a >= 39 invalid
    if (!colinb) { mLo = 0; mHi = 0; }
    fL0 &= mLo; fL1 &= mLo; fL2 &= mLo; fL3 &= mLo;
    fH0 &= mHi; fH1 &= mHi; fH2 &= mHi; fH3 &= mHi;
  }

  // ---- phase 2: issue logits row-group 0 (hides under morphology) ----
  const bool outl = (lane >= 2) && (lane < 56);   // 54 lanes x 4 = 216 cols
  const float* pg = lg + (size_t)gr0 * W_ + cbc;
  float4 ga0[8], ga1[8];   // buffer A: ch0/ch1 of one 8-row group
  float4 gb0[8], gb1[8];   // buffer B
#define ISSUE(G0, G1, grp)                                                  \
  if (outl) {                                                               \
    const float* p_ = pg + (size_t)(8 * (grp)) * W_;                        \
    _Pragma("unroll") for (int o = 0; o < 8; ++o) {                         \
      G0[o] = *(const float4*)(p_ + (size_t)o * W_);                        \
      G1[o] = *(const float4*)(p_ + (size_t)o * W_ + HW);                   \
    }                                                                       \
  }
  ISSUE(ga0, ga1, 0)

  // ---- phase 3: horizontal 15-OR, exact per column over 4-col lanes ----
  // col 4l+0: sfx3(l-2)|all(l-1..l+1)       col 4l+1: sfx2|core|pfx1(l+2)
  // col 4l+2: sfx1|core|pfx2(l+2)           col 4l+3: all(l-1..l+1)|pfx3
  // shuffle garbage only reaches lanes outside [2,56) -> never consumed.
  const u64 allL = fL0 | fL1 | fL2 | fL3, allH = fH0 | fH1 | fH2 | fH3;
  const u64 s2L = fL2 | fL3, s2H = fH2 | fH3;
  const u64 s3L = fL1 | s2L, s3H = fH1 | s2H;
  const u64 p2L = fL0 | fL1, p2H = fH0 | fH1;
  const u64 p3L = p2L | fL2, p3H = p2H | fH2;
  const u64 coreL = shfl_up64(allL, 1) | allL | shfl_dn64(allL, 1);
  const u64 coreH = shfl_up64(allH, 1) | allH | shfl_dn64(allH, 1);
  u64 w0L = coreL | shfl_up64(s3L, 2);
  u64 w0H = coreH | shfl_up64(s3H, 2);
  u64 w1L = coreL | shfl_up64(s2L, 2) | shfl_dn64(fL0, 2);
  u64 w1H = coreH | shfl_up64(s2H, 2) | shfl_dn64(fH0, 2);
  u64 w2L = coreL | shfl_up64(fL3, 2) | shfl_dn64(p2L, 2);
  u64 w2H = coreH | shfl_up64(fH3, 2) | shfl_dn64(p2H, 2);
  u64 w3L = coreL | shfl_dn64(p3L, 2);
  u64 w3H = coreH | shfl_dn64(p3H, 2);

  // ---- phase 4: vertical 15-OR (lo bit 2o = OR over label rows o..o+14) --
  vfold15(w0L, w0H);
  vfold15(w1L, w1H);
  vfold15(w2L, w2H);
  vfold15(w3L, w3H);

  // ---- phase 5: 4 row-groups, software-pipelined (issue next, consume cur)
  double lsum = 0.0;
  unsigned lcnt = 0;
#define CONSUME(G0, G1, grp)                                                \
  if (outl) {                                                               \
    _Pragma("unroll") for (int o = 0; o < 8; ++o) {                         \
      const int ro = 8 * (grp) + o;                                         \
      const unsigned b0 = (unsigned)(w0L >> (2 * ro)) & 3u;                 \
      const unsigned b1 = (unsigned)(w1L >> (2 * ro)) & 3u;                 \
      const unsigned b2 = (unsigned)(w2L >> (2 * ro)) & 3u;                 \
      const unsigned b3 = (unsigned)(w3L >> (2 * ro)) & 3u;                 \
      const unsigned q0 = (unsigned)(cp0 >> (2 * ro)) & 3u;                 \
      const unsigned q1 = (unsigned)(cp1 >> (2 * ro)) & 3u;                 \
      const unsigned q2 = (unsigned)(cp2 >> (2 * ro)) & 3u;                 \
      const unsigned q3 = (unsigned)(cp3 >> (2 * ro)) & 3u;                 \
      const float4 A = G0[o], C = G1[o];                                    \
      const bool k0 = (b0 == 3u) && !(q0 & 2u);                             \
      const bool k1 = (b1 == 3u) && !(q1 & 2u);                             \
      const bool k2 = (b2 == 3u) && !(q2 & 2u);                             \
      const bool k3 = (b3 == 3u) && !(q3 & 2u);                             \
      lsum += k0 ? (double)((q0 & 1u) ? C.x : A.x) : 0.0;                   \
      lsum += k1 ? (double)((q1 & 1u) ? C.y : A.y) : 0.0;                   \
      lsum += k2 ? (double)((q2 & 1u) ? C.z : A.z) : 0.0;                   \
      lsum += k3 ? (double)((q3 & 1u) ? C.w : A.w) : 0.0;                   \
      lcnt += (unsigned)k0 + k1 + k2 + k3;                                  \
    }                                                                       \
  }
  ISSUE(gb0, gb1, 1)
  CONSUME(ga0, ga1, 0)
  ISSUE(ga0, ga1, 2)
  CONSUME(gb0, gb1, 1)
  ISSUE(gb0, gb1, 3)
  CONSUME(ga0, ga1, 2)
  CONSUME(gb0, gb1, 3)
#undef ISSUE
#undef CONSUME

  // ---- wave reduction -> one double2 per block (single-wave block) ----
#pragma unroll
  for (int off = 32; off > 0; off >>= 1) {
    lsum += __shfl_down(lsum, off, 64);
    lcnt += __shfl_down(lcnt, off, 64);
  }
  if (lane == 0) partials[bid] = make_double2(lsum, (double)lcnt);
}

extern "C" __global__ __launch_bounds__(1024)
void boundary_loss_final(const double2* __restrict__ partials,
                         float* __restrict__ out)
{
  __shared__ double red_s[16];
  __shared__ double red_c[16];
  const int tid = threadIdx.x;
  double s = 0.0, c = 0.0;
  for (int i = tid; i < NTILE; i += 1024) {
    const double2 p = partials[i];
    s += p.x;
    c += p.y;
  }
#pragma unroll
  for (int off = 32; off > 0; off >>= 1) {
    s += __shfl_down(s, off, 64);
    c += __shfl_down(c, off, 64);
  }
  const int wave = tid >> 6;
  if ((tid & 63) == 0) { red_s[wave] = s; red_c[wave] = c; }
  __syncthreads();
  if (tid == 0) {
    double ts = 0.0, tc = 0.0;
#pragma unroll
    for (int i = 0; i < 16; ++i) { ts += red_s[i]; tc += red_c[i]; }
    if (tc < 1.0) tc = 1.0;
    out[0] = (float)(-ts / tc);
  }
}

extern "C" void kernel_launch(void* const* d_in, const int* in_sizes, int n_in,
                              void* d_out, int out_size, void* d_ws, size_t ws_size,
                              hipStream_t stream)
{
  const float* logits = (const float*)d_in[0];
  const int* labels = (const int*)d_in[1];
  float* out = (float*)d_out;
  double2* partials = (double2*)d_ws;  // NTILE*16 B = 30,720 B; every slot
                                       // written by main -> no init needed.

  boundary_loss_main<<<dim3(NTILE), 64, 0, stream>>>(logits, labels, partials);
  boundary_loss_final<<<1, 1024, 0, stream>>>(partials, out);
}